// Round 1
// 276.975 us; speedup vs baseline: 1.0524x; 1.0524x over previous
//
#include <hip/hip_runtime.h>
#include <math.h>

#define BLOCK 256
#define GRID  2048          // 8192 dual-tiles / 2048 = 4 iters per block

typedef _Float16 half8 __attribute__((ext_vector_type(8)));
typedef float    f32x4 __attribute__((ext_vector_type(4)));

// Output-column permutation: producer layer writes logical out-feat
// phi(nt, i) into MFMA out-slot (nt, i). Then lane (m,q)'s C quads
// (acc[nt][r] = feat phi(nt, q*4+r)) packed pairwise give exactly the
// consumer B-frag halves (feats kt*32 + q*8 + j, j=0..7) with ZERO data
// movement: activations chain lane-locally through registers.
__device__ __forceinline__ int phi(int nt, int m) {
    return ((nt >> 1) << 5) + ((m >> 2) << 3) + ((nt & 1) << 2) + (m & 3);
}

// A-operand weight fragment: lane (m,q) holds A[i=m][k=q*8+j] = w[k][nsrc].
// w row-major [Kreal, N0]; out-of-range k or !valid -> 0.
__device__ __forceinline__ half8 bfragW(const float* __restrict__ w, int N0,
                                        int nsrc, int k0, int Kreal, bool valid) {
    half8 r;
    #pragma unroll
    for (int j = 0; j < 8; j++) {
        int k = k0 + j;
        float v = (valid && k < Kreal) ? w[k * N0 + nsrc] : 0.f;
        r[j] = (_Float16)v;
    }
    return r;
}

__device__ __forceinline__ half8 packrelu(f32x4 a, f32x4 b) {
    half8 h;
    #pragma unroll
    for (int r = 0; r < 4; r++) {
        h[r]     = (_Float16)fmaxf(a[r], 0.f);
        h[4 + r] = (_Float16)fmaxf(b[r], 0.f);
    }
    return h;
}

__device__ __forceinline__ half8 packraw(f32x4 a, f32x4 b) {
    half8 h;
    #pragma unroll
    for (int r = 0; r < 4; r++) {
        h[r]     = (_Float16)a[r];
        h[4 + r] = (_Float16)b[r];
    }
    return h;
}

__device__ __forceinline__ void sh16(float x, float y, float z, float* e) {
    float xx = x * x, yy = y * y, zz = z * z;
    float xy = x * y, yz = y * z, xz = x * z;
    e[0]  = 0.28209479177387814f;
    e[1]  = -0.48860251190291987f * y;
    e[2]  = 0.48860251190291987f * z;
    e[3]  = -0.48860251190291987f * x;
    e[4]  = 1.0925484305920792f * xy;
    e[5]  = -1.0925484305920792f * yz;
    e[6]  = 0.94617469575756f * zz - 0.31539156525252005f;
    e[7]  = -1.0925484305920792f * xz;
    e[8]  = 0.5462742152960396f * (xx - yy);
    e[9]  = 0.5900435899266435f * y * (3.0f * xx - yy);
    e[10] = 2.890611442640554f * xy * z;
    e[11] = 0.4570457994644657f * y * (4.0f * zz - xx - yy);
    e[12] = 0.3731763325901154f * z * (2.0f * zz - 3.0f * xx - 3.0f * yy);
    e[13] = 0.4570457994644657f * x * (4.0f * zz - xx - yy);
    e[14] = 1.445305721320277f * z * (xx - yy);
    e[15] = 0.5900435899266435f * x * (xx - 3.0f * yy);
}

#define MFMA(A, B, C) __builtin_amdgcn_mfma_f32_16x16x32_f16((A), (B), (C), 0, 0, 0)

// ---- LDS weight-fragment table: 40 frags x 64 lanes x 16B = 40 KiB ----
// (exactly 4 blocks/CU of LDS; frees ~160 VGPRs/lane of loop-invariant
//  weight state so occupancy is register-feasible at 3-4 waves/SIMD)
#define NFRAG  40
#define F_SIG0 0    // 4  frags  [nt]
#define F_COL0 4    // 8  frags  [nt*2+kt]
#define F_VIS0 12   // 8  frags  [nt*2+kt]
#define F_SIG1 20   // 4  frags  [nt*2+kt], nt<2
#define F_VIS1 24   // 2  frags  [kt]
#define F_COL1 26   // 12 frags  [nt*3+kt]
#define F_COL2 38   // 2  frags  [kt]

__global__ __launch_bounds__(BLOCK, 3) void nerf_lds(
    const float* __restrict__ x_feat,
    const float* __restrict__ dvec,
    const float* __restrict__ lvec,
    const float* __restrict__ w_sig0,   // [32,64]
    const float* __restrict__ w_sig1,   // [64,16]
    const float* __restrict__ w_col0,   // [64,64]
    const float* __restrict__ w_col1,   // [79,64]
    const float* __restrict__ w_col2,   // [64,3]
    const float* __restrict__ w_vis0,   // [48,64]
    const float* __restrict__ w_vis1,   // [64,1]
    float* __restrict__ out, int n)
{
    const int tid  = threadIdx.x;
    const int wv   = tid >> 6;
    const int lane = tid & 63;
    const int m    = lane & 15;
    const int q    = lane >> 4;

    __shared__ half8 WL[NFRAG * 64];

    // ---------- one-time staging: each wave fills a subset of frags ----------
    if (wv == 0) {
        #pragma unroll
        for (int nt = 0; nt < 4; nt++)
            WL[(F_SIG0 + nt) * 64 + lane] =
                bfragW(w_sig0, 64, phi(nt, m), q * 8, 32, true);
        // sig1 -> geo, widened to 32 out-cols with zero pads (col1 kt=2 layout)
        #pragma unroll
        for (int nt = 0; nt < 2; nt++)
            #pragma unroll
            for (int kt = 0; kt < 2; kt++) {
                int g = ((m >> 2) << 3) + ((nt & 1) << 2) + (m & 3);
                bool valid = ((m >> 2) < 2) && (g < 15);
                WL[(F_SIG1 + nt * 2 + kt) * 64 + lane] =
                    bfragW(w_sig1, 16, g + 1, kt * 32 + q * 8, 64, valid);
            }
        #pragma unroll
        for (int kt = 0; kt < 2; kt++)
            WL[(F_VIS1 + kt) * 64 + lane] =
                bfragW(w_vis1, 1, 0, kt * 32 + q * 8, 64, m == 0);
    } else if (wv == 1) {
        #pragma unroll
        for (int nt = 0; nt < 4; nt++)
            #pragma unroll
            for (int kt = 0; kt < 2; kt++)
                WL[(F_COL0 + nt * 2 + kt) * 64 + lane] =
                    bfragW(w_col0, 64, phi(nt, m), kt * 32 + q * 8, 64, true);
        #pragma unroll
        for (int kt = 0; kt < 2; kt++)
            WL[(F_COL2 + kt) * 64 + lane] =
                bfragW(w_col2, 3, m, kt * 32 + q * 8, 64, m < 3);
    } else if (wv == 2) {
        #pragma unroll
        for (int nt = 0; nt < 4; nt++)
            #pragma unroll
            for (int kt = 0; kt < 2; kt++)   // k rows 48..63 zero (denc unused)
                WL[(F_VIS0 + nt * 2 + kt) * 64 + lane] =
                    bfragW(w_vis0, 64, phi(nt, m), kt * 32 + q * 8, 48, true);
    } else {
        #pragma unroll
        for (int nt = 0; nt < 4; nt++)
            #pragma unroll
            for (int kt = 0; kt < 3; kt++)   // K=79; rows 79..95 zero
                WL[(F_COL1 + nt * 3 + kt) * 64 + lane] =
                    bfragW(w_col1, 64, phi(nt, m), kt * 32 + q * 8, 79, true);
    }
    __syncthreads();
    // Weights are read-only from here: NO barriers in the main loop.

    int wl = lane;   // LDS element offset; made loop-opaque below to stop
                     // LICM from hoisting 40 frag reads back into registers.
    #define LW(f) WL[wl + (f) * 64]

    const f32x4 z = {0.f, 0.f, 0.f, 0.f};
    const int ntiles = n >> 7;           // 128 points per block, 32 per wave
    for (int t = blockIdx.x; t < ntiles; t += GRID) {
        asm volatile("" : "+v"(wl));     // block LICM/CSE of LW() across iters

        const int pt0 = (t << 7) + wv * 32 + m;   // chain A point
        const int pt1 = pt0 + 16;                 // chain B point

        // ---- input frag kt=0: x[m][q*8 .. q*8+7] straight from global ----
        half8 fA0, fB0;
        {
            const float4* xa = (const float4*)(x_feat + (size_t)pt0 * 32 + q * 8);
            float4 v0 = xa[0], v1 = xa[1];
            fA0[0] = (_Float16)v0.x; fA0[1] = (_Float16)v0.y;
            fA0[2] = (_Float16)v0.z; fA0[3] = (_Float16)v0.w;
            fA0[4] = (_Float16)v1.x; fA0[5] = (_Float16)v1.y;
            fA0[6] = (_Float16)v1.z; fA0[7] = (_Float16)v1.w;
            const float4* xb = (const float4*)(x_feat + (size_t)pt1 * 32 + q * 8);
            float4 u0 = xb[0], u1 = xb[1];
            fB0[0] = (_Float16)u0.x; fB0[1] = (_Float16)u0.y;
            fB0[2] = (_Float16)u0.z; fB0[3] = (_Float16)u0.w;
            fB0[4] = (_Float16)u1.x; fB0[5] = (_Float16)u1.y;
            fB0[6] = (_Float16)u1.z; fB0[7] = (_Float16)u1.w;
        }

        // ---- input frag kt=1: SH in-lane. q<2 -> lenc, q>=2 -> denc;
        //      (q&1)==0 -> comps 0..7, ==1 -> comps 8..15 ----
        half8 fA1, fB1;
        {
            const float* va = (q < 2 ? lvec : dvec) + (size_t)pt0 * 3;
            float ea[16];
            sh16(va[0], va[1], va[2], ea);
            #pragma unroll
            for (int u = 0; u < 8; u++) {
                float s = (q & 1) ? ea[8 + u] : ea[u];   // select in f32
                fA1[u] = (_Float16)s;
            }
            const float* vb = (q < 2 ? lvec : dvec) + (size_t)pt1 * 3;
            float eb[16];
            sh16(vb[0], vb[1], vb[2], eb);
            #pragma unroll
            for (int u = 0; u < 8; u++) {
                float s = (q & 1) ? eb[8 + u] : eb[u];
                fB1[u] = (_Float16)s;
            }
        }

        f32x4 a0, a1, a2, a3, b0, b1, b2, b3;
        half8 w;

        // ---- sig0: h = relu(x @ w_sig0), K=32 ----
        a0 = z; a1 = z; a2 = z; a3 = z; b0 = z; b1 = z; b2 = z; b3 = z;
        w = LW(F_SIG0 + 0); a0 = MFMA(w, fA0, a0); b0 = MFMA(w, fB0, b0);
        w = LW(F_SIG0 + 1); a1 = MFMA(w, fA0, a1); b1 = MFMA(w, fB0, b1);
        w = LW(F_SIG0 + 2); a2 = MFMA(w, fA0, a2); b2 = MFMA(w, fB0, b2);
        w = LW(F_SIG0 + 3); a3 = MFMA(w, fA0, a3); b3 = MFMA(w, fB0, b3);
        half8 hK0a = packrelu(a0, a1), hK1a = packrelu(a2, a3);
        half8 hK0b = packrelu(b0, b1), hK1b = packrelu(b2, b3);

        // ---- col0: hc = relu([x|lenc|denc] @ w_col0), K=64 ----
        a0 = z; a1 = z; a2 = z; a3 = z; b0 = z; b1 = z; b2 = z; b3 = z;
        w = LW(F_COL0 + 0); a0 = MFMA(w, fA0, a0); b0 = MFMA(w, fB0, b0);
        w = LW(F_COL0 + 1); a0 = MFMA(w, fA1, a0); b0 = MFMA(w, fB1, b0);
        w = LW(F_COL0 + 2); a1 = MFMA(w, fA0, a1); b1 = MFMA(w, fB0, b1);
        w = LW(F_COL0 + 3); a1 = MFMA(w, fA1, a1); b1 = MFMA(w, fB1, b1);
        w = LW(F_COL0 + 4); a2 = MFMA(w, fA0, a2); b2 = MFMA(w, fB0, b2);
        w = LW(F_COL0 + 5); a2 = MFMA(w, fA1, a2); b2 = MFMA(w, fB1, b2);
        w = LW(F_COL0 + 6); a3 = MFMA(w, fA0, a3); b3 = MFMA(w, fB0, b3);
        w = LW(F_COL0 + 7); a3 = MFMA(w, fA1, a3); b3 = MFMA(w, fB1, b3);
        half8 cK0a = packrelu(a0, a1), cK1a = packrelu(a2, a3);
        half8 cK0b = packrelu(b0, b1), cK1b = packrelu(b2, b3);

        // ---- vis0: hv = relu([x|lenc|0] @ w_vis0), K=64 (rows 48+ zero) ----
        a0 = z; a1 = z; a2 = z; a3 = z; b0 = z; b1 = z; b2 = z; b3 = z;
        w = LW(F_VIS0 + 0); a0 = MFMA(w, fA0, a0); b0 = MFMA(w, fB0, b0);
        w = LW(F_VIS0 + 1); a0 = MFMA(w, fA1, a0); b0 = MFMA(w, fB1, b0);
        w = LW(F_VIS0 + 2); a1 = MFMA(w, fA0, a1); b1 = MFMA(w, fB0, b1);
        w = LW(F_VIS0 + 3); a1 = MFMA(w, fA1, a1); b1 = MFMA(w, fB1, b1);
        w = LW(F_VIS0 + 4); a2 = MFMA(w, fA0, a2); b2 = MFMA(w, fB0, b2);
        w = LW(F_VIS0 + 5); a2 = MFMA(w, fA1, a2); b2 = MFMA(w, fB1, b2);
        w = LW(F_VIS0 + 6); a3 = MFMA(w, fA0, a3); b3 = MFMA(w, fB0, b3);
        w = LW(F_VIS0 + 7); a3 = MFMA(w, fA1, a3); b3 = MFMA(w, fB1, b3);
        half8 vK0a = packrelu(a0, a1), vK1a = packrelu(a2, a3);
        half8 vK0b = packrelu(b0, b1), vK1b = packrelu(b2, b3);

        // ---- sig1: geo = h @ w_sig1[:,1:16] (no relu), 32 padded cols ----
        a0 = z; a1 = z; b0 = z; b1 = z;
        w = LW(F_SIG1 + 0); a0 = MFMA(w, hK0a, a0); b0 = MFMA(w, hK0b, b0);
        w = LW(F_SIG1 + 1); a0 = MFMA(w, hK1a, a0); b0 = MFMA(w, hK1b, b0);
        w = LW(F_SIG1 + 2); a1 = MFMA(w, hK0a, a1); b1 = MFMA(w, hK0b, b1);
        w = LW(F_SIG1 + 3); a1 = MFMA(w, hK1a, a1); b1 = MFMA(w, hK1b, b1);
        half8 gA = packraw(a0, a1), gB = packraw(b0, b1);

        // ---- vis1 + sigmoid: value lands at lane q==0, r=0 ----
        f32x4 va = z, vb = z;
        w = LW(F_VIS1 + 0); va = MFMA(w, vK0a, va); vb = MFMA(w, vK0b, vb);
        w = LW(F_VIS1 + 1); va = MFMA(w, vK1a, va); vb = MFMA(w, vK1b, vb);
        float visA = 1.f / (1.f + expf(-va[0]));
        float visB = 1.f / (1.f + expf(-vb[0]));

        // ---- col1: h2 = relu([hc|geo] @ w_col1), K=96 padded ----
        a0 = z; a1 = z; a2 = z; a3 = z; b0 = z; b1 = z; b2 = z; b3 = z;
        w = LW(F_COL1 + 0);  a0 = MFMA(w, cK0a, a0); b0 = MFMA(w, cK0b, b0);
        w = LW(F_COL1 + 1);  a0 = MFMA(w, cK1a, a0); b0 = MFMA(w, cK1b, b0);
        w = LW(F_COL1 + 2);  a0 = MFMA(w, gA,   a0); b0 = MFMA(w, gB,   b0);
        w = LW(F_COL1 + 3);  a1 = MFMA(w, cK0a, a1); b1 = MFMA(w, cK0b, b1);
        w = LW(F_COL1 + 4);  a1 = MFMA(w, cK1a, a1); b1 = MFMA(w, cK1b, b1);
        w = LW(F_COL1 + 5);  a1 = MFMA(w, gA,   a1); b1 = MFMA(w, gB,   b1);
        w = LW(F_COL1 + 6);  a2 = MFMA(w, cK0a, a2); b2 = MFMA(w, cK0b, b2);
        w = LW(F_COL1 + 7);  a2 = MFMA(w, cK1a, a2); b2 = MFMA(w, cK1b, b2);
        w = LW(F_COL1 + 8);  a2 = MFMA(w, gA,   a2); b2 = MFMA(w, gB,   b2);
        w = LW(F_COL1 + 9);  a3 = MFMA(w, cK0a, a3); b3 = MFMA(w, cK0b, b3);
        w = LW(F_COL1 + 10); a3 = MFMA(w, cK1a, a3); b3 = MFMA(w, cK1b, b3);
        w = LW(F_COL1 + 11); a3 = MFMA(w, gA,   a3); b3 = MFMA(w, gB,   b3);
        half8 h2K0a = packrelu(a0, a1), h2K1a = packrelu(a2, a3);
        half8 h2K0b = packrelu(b0, b1), h2K1b = packrelu(b2, b3);

        // ---- col2: color = relu(h2 @ w_col2) * vis; rows 0..2 at q==0 ----
        f32x4 ca = z, cb = z;
        w = LW(F_COL2 + 0); ca = MFMA(w, h2K0a, ca); cb = MFMA(w, h2K0b, cb);
        w = LW(F_COL2 + 1); ca = MFMA(w, h2K1a, ca); cb = MFMA(w, h2K1b, cb);
        if (q == 0) {
            float* oa = out + (size_t)pt0 * 3;
            oa[0] = fmaxf(ca[0], 0.f) * visA;
            oa[1] = fmaxf(ca[1], 0.f) * visA;
            oa[2] = fmaxf(ca[2], 0.f) * visA;
            float* ob = out + (size_t)pt1 * 3;
            ob[0] = fmaxf(cb[0], 0.f) * visB;
            ob[1] = fmaxf(cb[1], 0.f) * visB;
            ob[2] = fmaxf(cb[2], 0.f) * visB;
        }
    }
    #undef LW
}

extern "C" void kernel_launch(void* const* d_in, const int* in_sizes, int n_in,
                              void* d_out, int out_size, void* d_ws, size_t ws_size,
                              hipStream_t stream) {
    const float* x_feat = (const float*)d_in[0];
    const float* dvec   = (const float*)d_in[1];
    const float* lvec   = (const float*)d_in[2];
    const float* w_sig0 = (const float*)d_in[3];
    const float* w_sig1 = (const float*)d_in[4];
    const float* w_col0 = (const float*)d_in[5];
    const float* w_col1 = (const float*)d_in[6];
    const float* w_col2 = (const float*)d_in[7];
    const float* w_vis0 = (const float*)d_in[8];
    const float* w_vis1 = (const float*)d_in[9];
    float* out = (float*)d_out;

    const int n = in_sizes[0] / 32;   // N points (1048576: multiple of 128)
    nerf_lds<<<GRID, BLOCK, 0, stream>>>(x_feat, dvec, lvec,
                                         w_sig0, w_sig1, w_col0, w_col1,
                                         w_col2, w_vis0, w_vis1, out, n);
}